// Round 3
// baseline (676.886 us; speedup 1.0000x reference)
//
#include <hip/hip_runtime.h>
#include <stdint.h>

#define N_NODES 20000
#define N_EDGES 320000

typedef __attribute__((ext_vector_type(8)))  __bf16        bf16x8;
typedef __attribute__((ext_vector_type(16))) float         f32x16;
typedef __attribute__((ext_vector_type(4)))  float         f32x4v;
typedef __attribute__((ext_vector_type(8)))  unsigned short us8;
typedef __attribute__((ext_vector_type(4)))  unsigned short us4;
typedef __attribute__((ext_vector_type(2)))  unsigned short us2;

static __device__ __forceinline__ unsigned short cvt_bf16(float f) {
  uint32_t u = __builtin_bit_cast(uint32_t, f);
  u = (u + 0x7fffu + ((u >> 16) & 1u)) >> 16;
  return (unsigned short)u;
}
static __device__ __forceinline__ float cvt_f32(unsigned short h) {
  uint32_t u = ((uint32_t)h) << 16;
  return __builtin_bit_cast(float, u);
}

// ---------------------------------------------------------------------------
// Pack row-major f32 W[K][Ncols] into MFMA A/B fragment order (bf16):
// out[((ks*(Ncols/32)+nt)*64+lane)*8+e] = W[ks*16+(lane>>5)*8+e][nt*32+(lane&31)]
// (verified R1/R2)
// ---------------------------------------------------------------------------
__global__ void pack_w(const float* __restrict__ W, unsigned short* __restrict__ out,
                       int K, int Ncols) {
  int idx = blockIdx.x * 256 + threadIdx.x;
  int total = K * Ncols;
  if (idx >= total) return;
  int e    = idx & 7;
  int lane = (idx >> 3) & 63;
  int t    = idx >> 9;
  int ntiles = Ncols >> 5;
  int nt = t % ntiles;
  int ks = t / ntiles;
  int k = ks * 16 + (lane >> 5) * 8 + e;
  int c = nt * 32 + (lane & 31);
  out[idx] = cvt_bf16(W[(size_t)k * Ncols + c]);
}

// ---------------------------------------------------------------------------
// CSR build for segment_sum (receivers constant across iterations)
// ---------------------------------------------------------------------------
__global__ void hist_k(const int* __restrict__ recv, int* __restrict__ cnt, int n) {
  int i = blockIdx.x * 256 + threadIdx.x;
  if (i < n) atomicAdd(&cnt[recv[i]], 1);
}

__global__ void scan_k(const int* __restrict__ cnt, int* __restrict__ off,
                       int* __restrict__ cursor, int n) {
  __shared__ int part[1024];
  int t = threadIdx.x;
  int chunk = (n + 1023) / 1024;
  int base = t * chunk;
  int s = 0;
  for (int i = 0; i < chunk; ++i) { int idx = base + i; if (idx < n) s += cnt[idx]; }
  part[t] = s;
  __syncthreads();
  for (int d = 1; d < 1024; d <<= 1) {
    int v = (t >= d) ? part[t - d] : 0;
    __syncthreads();
    part[t] += v;
    __syncthreads();
  }
  int prefix = (t > 0) ? part[t - 1] : 0;
  for (int i = 0; i < chunk; ++i) {
    int idx = base + i;
    if (idx < n) { off[idx] = prefix; cursor[idx] = prefix; prefix += cnt[idx]; }
  }
  if (t == 1023) off[n] = part[1023];
}

__global__ void fill_k(const int* __restrict__ recv, int* __restrict__ cursor,
                       int* __restrict__ eid, int n) {
  int i = blockIdx.x * 256 + threadIdx.x;
  if (i < n) {
    int p = atomicAdd(&cursor[recv[i]], 1);
    eid[p] = i;
  }
}

// agg[n][:] = sum_{edges -> n} e[edge][:], f32 accumulate, bf16 out
__global__ void agg_k(const unsigned short* __restrict__ eb, const int* __restrict__ off,
                      const int* __restrict__ eid, unsigned short* __restrict__ aggb, int n) {
  int node = blockIdx.x * 4 + (threadIdx.x >> 6);
  if (node >= n) return;
  int lane = threadIdx.x & 63;
  float a0 = 0.f, a1 = 0.f;
  int s = off[node], t = off[node + 1];
  for (int q = s; q < t; ++q) {
    int ei = eid[q];
    us2 v = *(const us2*)(eb + (size_t)ei * 128 + lane * 2);
    a0 += cvt_f32(v[0]);
    a1 += cvt_f32(v[1]);
  }
  us2 r; r[0] = cvt_bf16(a0); r[1] = cvt_bf16(a1);
  *(us2*)(aggb + (size_t)node * 128 + lane * 2) = r;
}

// ---------------------------------------------------------------------------
// Fused 2-layer MLP, barrier-free main loops (direct-to-register operands):
//   out = relu(relu(A@W1+b1)@W2+b2), hidden 256, out 128.
//   MODE 0: A = srcf (f32, KIN=128)
//   MODE 1: A = [x[snd], x[rcv], e]  bf16 (KIN=384, per-lane gather)
//   MODE 2: A = [x, agg]             bf16 (KIN=256)
// 128 rows/block, 4 waves (256 thr). Layer 1 flipped (D1^T = W1f @ A^T):
//   wave (wm = wid>>1) computes hidden half wm*128, rows wp*64..+64 (2 tiles).
// Weights + rows load straight from global (L2-resident) -> no barriers.
// LDS only for the H transpose handoff (64 KB, one sync pair).
// ---------------------------------------------------------------------------
template <int KIN, int MODE, int POOL>
__global__ __launch_bounds__(256, 2)
void mlp_kernel(const float* __restrict__ srcf,
                const unsigned short* __restrict__ xb,
                const unsigned short* __restrict__ ebuf,
                const unsigned short* __restrict__ aggb,
                const int* __restrict__ senders,
                const int* __restrict__ receivers,
                const unsigned short* __restrict__ P1,
                const float* __restrict__ b1,
                const unsigned short* __restrict__ P2,
                const float* __restrict__ b2,
                unsigned short* __restrict__ dst,
                float* __restrict__ pool_out,
                int nrows) {
  __shared__ __align__(16) unsigned short Hs[32 * 128 * 8];  // 64 KB [slot][row][8]
  __shared__ float Ps[128];

  const int tid  = threadIdx.x;
  const int lane = tid & 63;
  const int wid  = tid >> 6;   // 0..3
  const int g    = lane >> 5;
  const int l31  = lane & 31;
  const int wm   = wid >> 1;   // hidden half
  const int wp   = wid & 1;    // row pair half
  const int rowBlock = blockIdx.x << 7;  // 128 rows/block

  // per-lane row bases for this wave's two 32-row tiles
  const unsigned short* rb[2][3];
  const float* fbp[2];
#pragma unroll
  for (int q = 0; q < 2; ++q) {
    int r = rowBlock + wp * 64 + q * 32 + l31;
    if (r >= nrows) r = nrows - 1;
    if constexpr (MODE == 0) {
      fbp[q] = srcf + (size_t)r * KIN;
    } else if constexpr (MODE == 1) {
      rb[q][0] = xb + (size_t)senders[r] * 128;
      rb[q][1] = xb + (size_t)receivers[r] * 128;
      rb[q][2] = ebuf + (size_t)r * 128;
    } else {
      rb[q][0] = xb + (size_t)r * 128;
      rb[q][1] = aggb + (size_t)r * 128;
    }
  }

  // ================= layer 1 (no barriers) =================
  f32x16 acc1[2][4];
#pragma unroll
  for (int q = 0; q < 2; ++q)
#pragma unroll
    for (int mt = 0; mt < 4; ++mt)
#pragma unroll
      for (int k = 0; k < 16; ++k) acc1[q][mt][k] = 0.0f;

  constexpr int NSEG = KIN / 128;
#pragma unroll
  for (int seg = 0; seg < NSEG; ++seg) {
#pragma unroll
    for (int cc = 0; cc < 8; ++cc) {
      const int c = seg * 8 + cc;
      const int k0 = cc * 16 + g * 8;   // element offset within 128-segment
      bf16x8 br[2];
#pragma unroll
      for (int q = 0; q < 2; ++q) {
        if constexpr (MODE == 0) {
          f32x4v a  = *(const f32x4v*)(fbp[q] + k0);
          f32x4v b4 = *(const f32x4v*)(fbp[q] + k0 + 4);
          us8 h;
#pragma unroll
          for (int e = 0; e < 4; ++e) { h[e] = cvt_bf16(a[e]); h[4 + e] = cvt_bf16(b4[e]); }
          br[q] = __builtin_bit_cast(bf16x8, h);
        } else {
          br[q] = __builtin_bit_cast(bf16x8, *(const us8*)(rb[q][seg] + k0));
        }
      }
      bf16x8 af[4];
#pragma unroll
      for (int mt = 0; mt < 4; ++mt)
        af[mt] = __builtin_bit_cast(bf16x8,
            *(const us8*)(P1 + (size_t)((c * 8 + wm * 4 + mt) * 64 + lane) * 8));
#pragma unroll
      for (int q = 0; q < 2; ++q)
#pragma unroll
        for (int mt = 0; mt < 4; ++mt)
          acc1[q][mt] = __builtin_amdgcn_mfma_f32_32x32x16_bf16(af[mt], br[q], acc1[q][mt], 0, 0, 0);
    }
  }

  // layer-1 epilogue: bias+relu -> Hs slot-major [hid/8][row][8]
#pragma unroll
  for (int q = 0; q < 2; ++q) {
    const int j = wp * 64 + q * 32 + l31;
#pragma unroll
    for (int mt = 0; mt < 4; ++mt) {
#pragma unroll
      for (int rq = 0; rq < 4; ++rq) {
        const int i0 = wm * 128 + mt * 32 + rq * 8 + g * 4;
        const f32x4v bb = *(const f32x4v*)(b1 + i0);
        us4 h;
#pragma unroll
        for (int e = 0; e < 4; ++e) {
          float v = acc1[q][mt][rq * 4 + e] + bb[e];
          h[e] = cvt_bf16(fmaxf(v, 0.0f));
        }
        *(us4*)(Hs + (i0 >> 3) * 1024 + j * 8 + g * 4) = h;
      }
    }
  }
  __syncthreads();

  // ================= layer 2 (no barriers) =================
  // wave wid owns rows wid*32..+32, all 128 output cols
  f32x16 acc2[4];
#pragma unroll
  for (int nt = 0; nt < 4; ++nt)
#pragma unroll
    for (int k = 0; k < 16; ++k) acc2[nt][k] = 0.0f;

#pragma unroll
  for (int s = 0; s < 16; ++s) {
    bf16x8 ah = __builtin_bit_cast(bf16x8,
        *(const us8*)(Hs + (s * 2 + g) * 1024 + (wid * 32 + l31) * 8));
#pragma unroll
    for (int nt = 0; nt < 4; ++nt) {
      bf16x8 bw = __builtin_bit_cast(bf16x8,
          *(const us8*)(P2 + (size_t)((s * 4 + nt) * 64 + lane) * 8));
      acc2[nt] = __builtin_amdgcn_mfma_f32_32x32x16_bf16(ah, bw, acc2[nt], 0, 0, 0);
    }
  }

  // layer-2 epilogue: bias+relu, bf16 store (+ fused pool row-sums)
#pragma unroll
  for (int reg = 0; reg < 16; ++reg) {
    const int j = wid * 32 + (reg & 3) + ((reg >> 2) << 3) + g * 4;
    const int row = rowBlock + j;
    float vsum = 0.0f;
#pragma unroll
    for (int nt = 0; nt < 4; ++nt) {
      const int c = nt * 32 + l31;
      float v = acc2[nt][reg] + b2[c];
      v = fmaxf(v, 0.0f);
      vsum += v;
      if (row < nrows) dst[(size_t)row * 128 + c] = cvt_bf16(v);
    }
    if constexpr (POOL) {
#pragma unroll
      for (int m = 1; m <= 16; m <<= 1) vsum += __shfl_xor(vsum, m, 64);
      if (l31 == 0) Ps[j] = vsum;
    }
  }
  if constexpr (POOL) {
    __syncthreads();
    if (tid < 128) {
      const int row = rowBlock + tid;
      if (row < nrows) pool_out[row] = Ps[tid];
    }
  }
}

// ---------------------------------------------------------------------------
// Workspace layout (bytes)
// ---------------------------------------------------------------------------
static constexpr size_t OFF_X    = 0;                          // N*128*2
static constexpr size_t OFF_E    = 5120000;                    // E*128*2
static constexpr size_t OFF_AGG  = 87040000;                   // N*128*2 (bf16)
static constexpr size_t OFF_PN1  = 92160000;                   // 65536
static constexpr size_t OFF_PN2  = OFF_PN1 + 65536;
static constexpr size_t OFF_PE1  = OFF_PN2 + 65536;
static constexpr size_t OFF_PE2  = OFF_PE1 + 65536;
static constexpr size_t OFF_PD1  = OFF_PE2 + 65536;            // 196608
static constexpr size_t OFF_PD2  = OFF_PD1 + 196608;
static constexpr size_t OFF_PM1  = OFF_PD2 + 65536;            // 131072
static constexpr size_t OFF_PM2  = OFF_PM1 + 131072;
static constexpr size_t OFF_CNT  = OFF_PM2 + 65536;            // N*4
static constexpr size_t OFF_OFFS = OFF_CNT + 80000;            // (N+1)*4
static constexpr size_t OFF_CUR  = OFF_OFFS + 80004;           // N*4
static constexpr size_t OFF_EID  = OFF_CUR + 80000;            // E*4

extern "C" void kernel_launch(void* const* d_in, const int* in_sizes, int n_in,
                              void* d_out, int out_size, void* d_ws, size_t ws_size,
                              hipStream_t stream) {
  const float* nodes = (const float*)d_in[0];
  const float* edges = (const float*)d_in[1];
  const int* senders = (const int*)d_in[2];
  const int* receivers = (const int*)d_in[3];
  const float* Wn1 = (const float*)d_in[4];  const float* bn1 = (const float*)d_in[5];
  const float* Wn2 = (const float*)d_in[6];  const float* bn2 = (const float*)d_in[7];
  const float* We1 = (const float*)d_in[8];  const float* be1 = (const float*)d_in[9];
  const float* We2 = (const float*)d_in[10]; const float* be2 = (const float*)d_in[11];
  const float* Wed1 = (const float*)d_in[12]; const float* bed1 = (const float*)d_in[13];
  const float* Wed2 = (const float*)d_in[14]; const float* bed2 = (const float*)d_in[15];
  const float* Wnd1 = (const float*)d_in[16]; const float* bnd1 = (const float*)d_in[17];
  const float* Wnd2 = (const float*)d_in[18]; const float* bnd2 = (const float*)d_in[19];

  char* ws = (char*)d_ws;
  unsigned short* xb   = (unsigned short*)(ws + OFF_X);
  unsigned short* eb   = (unsigned short*)(ws + OFF_E);
  unsigned short* aggb = (unsigned short*)(ws + OFF_AGG);
  unsigned short* Pn1  = (unsigned short*)(ws + OFF_PN1);
  unsigned short* Pn2  = (unsigned short*)(ws + OFF_PN2);
  unsigned short* Pe1  = (unsigned short*)(ws + OFF_PE1);
  unsigned short* Pe2  = (unsigned short*)(ws + OFF_PE2);
  unsigned short* Pd1  = (unsigned short*)(ws + OFF_PD1);
  unsigned short* Pd2  = (unsigned short*)(ws + OFF_PD2);
  unsigned short* Pm1  = (unsigned short*)(ws + OFF_PM1);
  unsigned short* Pm2  = (unsigned short*)(ws + OFF_PM2);
  int* cnt    = (int*)(ws + OFF_CNT);
  int* offs   = (int*)(ws + OFF_OFFS);
  int* cursor = (int*)(ws + OFF_CUR);
  int* eid    = (int*)(ws + OFF_EID);
  float* outp = (float*)d_out;

  // pack all 8 weight matrices into MFMA fragment order (bf16)
  pack_w<<<128, 256, 0, stream>>>(Wn1, Pn1, 128, 256);
  pack_w<<<128, 256, 0, stream>>>(Wn2, Pn2, 256, 128);
  pack_w<<<128, 256, 0, stream>>>(We1, Pe1, 128, 256);
  pack_w<<<128, 256, 0, stream>>>(We2, Pe2, 256, 128);
  pack_w<<<384, 256, 0, stream>>>(Wed1, Pd1, 384, 256);
  pack_w<<<128, 256, 0, stream>>>(Wed2, Pd2, 256, 128);
  pack_w<<<256, 256, 0, stream>>>(Wnd1, Pm1, 256, 256);
  pack_w<<<128, 256, 0, stream>>>(Wnd2, Pm2, 256, 128);

  // CSR for segment_sum over receivers
  hipMemsetAsync(cnt, 0, (size_t)N_NODES * 4, stream);
  hist_k<<<1250, 256, 0, stream>>>(receivers, cnt, N_EDGES);
  scan_k<<<1, 1024, 0, stream>>>(cnt, offs, cursor, N_NODES);
  fill_k<<<1250, 256, 0, stream>>>(receivers, cursor, eid, N_EDGES);

  const int nodeBlocks = (N_NODES + 127) / 128;  // 157
  const int edgeBlocks = N_EDGES / 128;          // 2500

  // embed stage
  mlp_kernel<128, 0, 0><<<nodeBlocks, 256, 0, stream>>>(
      nodes, nullptr, nullptr, nullptr, nullptr, nullptr,
      Pn1, bn1, Pn2, bn2, xb, nullptr, N_NODES);
  mlp_kernel<128, 0, 0><<<edgeBlocks, 256, 0, stream>>>(
      edges, nullptr, nullptr, nullptr, nullptr, nullptr,
      Pe1, be1, Pe2, be2, eb, nullptr, N_EDGES);

  for (int it = 0; it < 2; ++it) {
    mlp_kernel<384, 1, 0><<<edgeBlocks, 256, 0, stream>>>(
        nullptr, xb, eb, nullptr, senders, receivers,
        Pd1, bed1, Pd2, bed2, eb, nullptr, N_EDGES);
    agg_k<<<(N_NODES + 3) / 4, 256, 0, stream>>>(eb, offs, eid, aggb, N_NODES);
    mlp_kernel<256, 2, 1><<<nodeBlocks, 256, 0, stream>>>(
        nullptr, xb, nullptr, aggb, nullptr, nullptr,
        Pm1, bnd1, Pm2, bnd2, xb, outp + (size_t)it * N_NODES, N_NODES);
  }
}

// Round 4
// 596.740 us; speedup vs baseline: 1.1343x; 1.1343x over previous
//
#include <hip/hip_runtime.h>
#include <stdint.h>

#define N_NODES 20000
#define N_EDGES 320000

typedef __attribute__((ext_vector_type(8)))  __bf16        bf16x8;
typedef __attribute__((ext_vector_type(16))) float         f32x16;
typedef __attribute__((ext_vector_type(4)))  float         f32x4v;
typedef __attribute__((ext_vector_type(8)))  unsigned short us8;
typedef __attribute__((ext_vector_type(4)))  unsigned short us4;
typedef __attribute__((ext_vector_type(2)))  unsigned short us2;

static __device__ __forceinline__ unsigned short cvt_bf16(float f) {
  uint32_t u = __builtin_bit_cast(uint32_t, f);
  u = (u + 0x7fffu + ((u >> 16) & 1u)) >> 16;
  return (unsigned short)u;
}
static __device__ __forceinline__ float cvt_f32(unsigned short h) {
  uint32_t u = ((uint32_t)h) << 16;
  return __builtin_bit_cast(float, u);
}

// async global->LDS, 16B per lane; LDS dest = wave-uniform base (HW adds lane*16)
static __device__ __forceinline__ void gll16(const void* g, void* l) {
  __builtin_amdgcn_global_load_lds(
      (const __attribute__((address_space(1))) unsigned int*)g,
      (__attribute__((address_space(3))) unsigned int*)l, 16, 0, 0);
}

// ---------------------------------------------------------------------------
// Pack row-major f32 W[K][Ncols] into MFMA A/B fragment order (bf16).
// out[((c*(Ncols/32)+nt)*64+lane)*8+e] = W[c*16+(lane>>5)*8+e][nt*32+(lane&31)]
// (verified R1-R3)
// ---------------------------------------------------------------------------
__global__ void pack_w(const float* __restrict__ W, unsigned short* __restrict__ out,
                       int K, int Ncols) {
  int idx = blockIdx.x * 256 + threadIdx.x;
  int total = K * Ncols;
  if (idx >= total) return;
  int e    = idx & 7;
  int lane = (idx >> 3) & 63;
  int t    = idx >> 9;
  int ntiles = Ncols >> 5;
  int nt = t % ntiles;
  int ks = t / ntiles;
  int k = ks * 16 + (lane >> 5) * 8 + e;
  int c = nt * 32 + (lane & 31);
  out[idx] = cvt_bf16(W[(size_t)k * Ncols + c]);
}

// ---------------------------------------------------------------------------
// CSR build for segment_sum (receivers constant across iterations)
// ---------------------------------------------------------------------------
__global__ void hist_k(const int* __restrict__ recv, int* __restrict__ cnt, int n) {
  int i = blockIdx.x * 256 + threadIdx.x;
  if (i < n) atomicAdd(&cnt[recv[i]], 1);
}

__global__ void scan_k(const int* __restrict__ cnt, int* __restrict__ off,
                       int* __restrict__ cursor, int n) {
  __shared__ int part[1024];
  int t = threadIdx.x;
  int chunk = (n + 1023) / 1024;
  int base = t * chunk;
  int s = 0;
  for (int i = 0; i < chunk; ++i) { int idx = base + i; if (idx < n) s += cnt[idx]; }
  part[t] = s;
  __syncthreads();
  for (int d = 1; d < 1024; d <<= 1) {
    int v = (t >= d) ? part[t - d] : 0;
    __syncthreads();
    part[t] += v;
    __syncthreads();
  }
  int prefix = (t > 0) ? part[t - 1] : 0;
  for (int i = 0; i < chunk; ++i) {
    int idx = base + i;
    if (idx < n) { off[idx] = prefix; cursor[idx] = prefix; prefix += cnt[idx]; }
  }
  if (t == 1023) off[n] = part[1023];
}

__global__ void fill_k(const int* __restrict__ recv, int* __restrict__ cursor,
                       int* __restrict__ eid, int n) {
  int i = blockIdx.x * 256 + threadIdx.x;
  if (i < n) {
    int p = atomicAdd(&cursor[recv[i]], 1);
    eid[p] = i;
  }
}

// agg[n][:] = sum_{edges -> n} e[edge][:], f32 accumulate, bf16 out
__global__ void agg_k(const unsigned short* __restrict__ eb, const int* __restrict__ off,
                      const int* __restrict__ eid, unsigned short* __restrict__ aggb, int n) {
  int node = blockIdx.x * 4 + (threadIdx.x >> 6);
  if (node >= n) return;
  int lane = threadIdx.x & 63;
  float a0 = 0.f, a1 = 0.f;
  int s = off[node], t = off[node + 1];
  for (int q = s; q < t; ++q) {
    int ei = eid[q];
    us2 v = *(const us2*)(eb + (size_t)ei * 128 + lane * 2);
    a0 += cvt_f32(v[0]);
    a1 += cvt_f32(v[1]);
  }
  us2 r; r[0] = cvt_bf16(a0); r[1] = cvt_bf16(a1);
  *(us2*)(aggb + (size_t)node * 128 + lane * 2) = r;
}

// ---------------------------------------------------------------------------
// Fused 2-layer MLP, 256 rows/block, 512 thr (8 waves), counted-vmcnt pipeline.
//   out = relu(relu(A@W1+b1)@W2+b2), hidden 256, out 128.
//   MODE 0: A = srcf (f32, reg-staged, plain-sync path)
//   MODE 1: A = [x[snd], x[rcv], e]  bf16 (KIN=384, global_load_lds gather)
//   MODE 2: A = [x, agg]             bf16 (KIN=256)
// Layer 1 flipped (D1^T = W1f @ A^T); wave-tile 128hid x 64rows (4x2 blocking).
// LDS: rows stage 3x16KB @0 + W1 stage 3x16KB @48K, both aliased under
//      Hs [32 pages][256 rows][16B] = 128KB; W2 stage 3x8KB @128K; pool @152K.
// K-step = 32. Two s_barriers/step; vmcnt never drains mid-loop (T3+T4).
// ---------------------------------------------------------------------------
template <int KIN, int MODE, int POOL>
__global__ __launch_bounds__(512, 2)
void mlp_kernel(const float* __restrict__ srcf,
                const unsigned short* __restrict__ xb,
                const unsigned short* __restrict__ ebuf,
                const unsigned short* __restrict__ aggb,
                const int* __restrict__ senders,
                const int* __restrict__ receivers,
                const unsigned short* __restrict__ P1,
                const float* __restrict__ b1,
                const unsigned short* __restrict__ P2,
                const float* __restrict__ b2,
                unsigned short* __restrict__ dst,
                float* __restrict__ pool_out,
                int nrows) {
  constexpr int NS1 = KIN / 32;
  __shared__ __align__(16) unsigned char lds[157696];

  const int tid  = threadIdx.x;
  const int lane = tid & 63;
  const int wid  = tid >> 6;     // 0..7
  const int g    = lane >> 5;
  const int l31  = lane & 31;
  const int rowBlock = blockIdx.x << 8;   // 256 rows/block

  const int wm = wid >> 2;   // L1 hid-half / L2 out-half / stage k-subpage
  const int wq = wid & 3;    // L1 row-quarter / L2 row-quarter / stage row-quarter

  const unsigned char* P1b = (const unsigned char*)P1;
  const unsigned char* P2b = (const unsigned char*)P2;

  // ---------------- stage identity ----------------
  const unsigned short* segp0 = nullptr;
  const unsigned short* segp1 = nullptr;
  const unsigned short* segp2 = nullptr;
  const float* fb = nullptr;
  int r0 = 0, h0 = 0;
  if constexpr (MODE == 0) {
    r0 = tid >> 1; h0 = tid & 1;
    int grm = rowBlock + r0; if (grm >= nrows) grm = nrows - 1;
    fb = srcf + (size_t)grm * KIN;
  } else {
    int gr = rowBlock + wq * 64 + lane; if (gr >= nrows) gr = nrows - 1;
    if constexpr (MODE == 1) {
      segp0 = xb + (size_t)senders[gr] * 128;
      segp1 = xb + (size_t)receivers[gr] * 128;
      segp2 = ebuf + (size_t)gr * 128;
    } else {
      segp0 = xb + (size_t)gr * 128;
      segp1 = aggb + (size_t)gr * 128;
    }
  }

  // per-lane row source for k-offset k0 (stays inside one 128-col segment)
  auto rowsrc = [&](int k0) -> const unsigned short* {
    const int seg = k0 >> 7, ko = k0 & 127;
    const unsigned short* p = segp0;
    if constexpr (MODE == 1) p = (seg == 0) ? segp0 : (seg == 1) ? segp1 : segp2;
    if constexpr (MODE == 2) p = (seg == 0) ? segp0 : segp1;
    return p + ko;
  };

  // stage rows+W1 chunk s into buffer (s%3)   [MODE 1/2: 4 glls/thread]
  auto STG1 = [&](int s) {
    const int bi = s % 3;
    unsigned char* bR = &lds[0] + bi * 16384;
    unsigned char* bW = &lds[49152] + bi * 16384;
#pragma unroll
    for (int j = 0; j < 2; ++j) {
      const int k0 = s * 32 + j * 16 + wm * 8;
      gll16(rowsrc(k0), bR + j * 8192 + wm * 4096 + wq * 1024);
      gll16(P1b + (size_t)s * 16384 + j * 8192 + wid * 1024 + lane * 16,
            bW + j * 8192 + wid * 1024);
    }
  };

  // ---- MODE 0 reg-staging (T14 split, plain-sync) ----
  f32x4v pA0, pA1, pB0, pB1;
  auto LD0 = [&](int s) {
    const float* p = fb + s * 32 + h0 * 16;
    pA0 = *(const f32x4v*)(p);
    pA1 = *(const f32x4v*)(p + 4);
    pB0 = *(const f32x4v*)(p + 8);
    pB1 = *(const f32x4v*)(p + 12);
  };
  auto WR0 = [&](int s) {
    unsigned char* bR = &lds[0] + (s & 1) * 16384;
    us8 ha, hb;
#pragma unroll
    for (int e = 0; e < 4; ++e) {
      ha[e] = cvt_bf16(pA0[e]); ha[4 + e] = cvt_bf16(pA1[e]);
      hb[e] = cvt_bf16(pB0[e]); hb[4 + e] = cvt_bf16(pB1[e]);
    }
    *(us8*)(bR + (h0 * 2 + 0) * 4096 + r0 * 16) = ha;
    *(us8*)(bR + (h0 * 2 + 1) * 4096 + r0 * 16) = hb;
  };
  auto STG1W0 = [&](int s) {
    unsigned char* bW = &lds[49152] + (s & 1) * 16384;
#pragma unroll
    for (int j = 0; j < 2; ++j)
      gll16(P1b + (size_t)s * 16384 + j * 8192 + wid * 1024 + lane * 16,
            bW + j * 8192 + wid * 1024);
  };

  // ================= layer 1 =================
  f32x16 acc1[4][2];
#pragma unroll
  for (int mt = 0; mt < 4; ++mt)
#pragma unroll
    for (int q = 0; q < 2; ++q)
#pragma unroll
      for (int k = 0; k < 16; ++k) acc1[mt][q][k] = 0.0f;

  auto L1STEP = [&](const unsigned char* bR, const unsigned char* bW) {
    bf16x8 af[2][4], br[2][2];
#pragma unroll
    for (int kc = 0; kc < 2; ++kc) {
#pragma unroll
      for (int mt = 0; mt < 4; ++mt)
        af[kc][mt] = __builtin_bit_cast(bf16x8,
            *(const us8*)(bW + kc * 8192 + (wm * 4 + mt) * 1024 + lane * 16));
#pragma unroll
      for (int q = 0; q < 2; ++q)
        br[kc][q] = __builtin_bit_cast(bf16x8,
            *(const us8*)(bR + (kc * 2 + g) * 4096 + (wq * 64 + q * 32 + l31) * 16));
    }
#pragma unroll
    for (int kc = 0; kc < 2; ++kc)
#pragma unroll
      for (int mt = 0; mt < 4; ++mt)
#pragma unroll
        for (int q = 0; q < 2; ++q)
          acc1[mt][q] = __builtin_amdgcn_mfma_f32_32x32x16_bf16(
              af[kc][mt], br[kc][q], acc1[mt][q], 0, 0, 0);
  };

  if constexpr (MODE == 0) {
    LD0(0); WR0(0); STG1W0(0);
    if (NS1 > 1) LD0(1);
    __syncthreads();
#pragma unroll 1
    for (int s = 0; s < NS1; ++s) {
      L1STEP(&lds[0] + (s & 1) * 16384, &lds[49152] + (s & 1) * 16384);
      if (s + 1 < NS1) {
        WR0(s + 1);
        STG1W0(s + 1);
        if (s + 2 < NS1) LD0(s + 2);
      }
      __syncthreads();
    }
  } else {
    STG1(0); STG1(1);
#pragma unroll 1
    for (int s = 0; s < NS1; ++s) {
      if (s + 2 < NS1) STG1(s + 2);
      const int rem = NS1 - 1 - s;
      if (rem >= 2)      asm volatile("s_waitcnt vmcnt(8)" ::: "memory");
      else if (rem == 1) asm volatile("s_waitcnt vmcnt(4)" ::: "memory");
      else               asm volatile("s_waitcnt vmcnt(0)" ::: "memory");
      asm volatile("s_barrier" ::: "memory");
      const int bi = s % 3;
      L1STEP(&lds[0] + bi * 16384, &lds[49152] + bi * 16384);
      asm volatile("s_barrier" ::: "memory");
    }
  }

  // layer-1 epilogue: bias+relu -> Hs [page = hid>>3][row][16B], halves at +g*8
#pragma unroll
  for (int mt = 0; mt < 4; ++mt) {
#pragma unroll
    for (int q = 0; q < 2; ++q) {
      const int j = wq * 64 + q * 32 + l31;
#pragma unroll
      for (int rq = 0; rq < 4; ++rq) {
        const int i0 = wm * 128 + mt * 32 + rq * 8 + g * 4;
        const f32x4v bb = *(const f32x4v*)(b1 + i0);
        us4 h;
#pragma unroll
        for (int e = 0; e < 4; ++e)
          h[e] = cvt_bf16(fmaxf(acc1[mt][q][rq * 4 + e] + bb[e], 0.0f));
        *(us4*)(&lds[0] + (size_t)(wm * 16 + mt * 4 + rq) * 4096 + j * 16 + g * 8) = h;
      }
    }
  }
  __syncthreads();   // full drain: Hs published, all prior VMEM retired

  // ================= layer 2 =================
  f32x16 acc2[2][2];
#pragma unroll
  for (int q = 0; q < 2; ++q)
#pragma unroll
    for (int nt = 0; nt < 2; ++nt)
#pragma unroll
      for (int k = 0; k < 16; ++k) acc2[q][nt][k] = 0.0f;

  auto STG2 = [&](int s) {
    gll16(P2b + (size_t)s * 8192 + wid * 1024 + lane * 16,
          &lds[131072] + (s % 3) * 8192 + wid * 1024);
  };

  STG2(0); STG2(1);
#pragma unroll 1
  for (int s = 0; s < 8; ++s) {
    if (s + 2 < 8) STG2(s + 2);
    const int rem = 7 - s;
    if (rem >= 2)      asm volatile("s_waitcnt vmcnt(2)" ::: "memory");
    else if (rem == 1) asm volatile("s_waitcnt vmcnt(1)" ::: "memory");
    else               asm volatile("s_waitcnt vmcnt(0)" ::: "memory");
    asm volatile("s_barrier" ::: "memory");
    const unsigned char* bW2 = &lds[131072] + (s % 3) * 8192;
    bf16x8 ah[2][2], bw[2][2];
#pragma unroll
    for (int kc = 0; kc < 2; ++kc) {
#pragma unroll
      for (int q = 0; q < 2; ++q)
        ah[kc][q] = __builtin_bit_cast(bf16x8,
            *(const us8*)(&lds[0] + (size_t)(s * 4 + kc * 2 + g) * 4096 +
                          (wq * 64 + q * 32 + l31) * 16));
#pragma unroll
      for (int nt = 0; nt < 2; ++nt)
        bw[kc][nt] = __builtin_bit_cast(bf16x8,
            *(const us8*)(bW2 + kc * 4096 + (wm * 2 + nt) * 1024 + lane * 16));
    }
#pragma unroll
    for (int kc = 0; kc < 2; ++kc)
#pragma unroll
      for (int q = 0; q < 2; ++q)
#pragma unroll
        for (int nt = 0; nt < 2; ++nt)
          acc2[q][nt] = __builtin_amdgcn_mfma_f32_32x32x16_bf16(
              ah[kc][q], bw[kc][nt], acc2[q][nt], 0, 0, 0);
    asm volatile("s_barrier" ::: "memory");
  }

  // layer-2 epilogue: bias+relu, bf16 store (+ fused pool partials)
  float* Ps = (float*)(&lds[155648]);   // [2][256]
#pragma unroll
  for (int q = 0; q < 2; ++q) {
    const float bias0 = b2[wm * 64 + l31];
    const float bias1 = b2[wm * 64 + 32 + l31];
#pragma unroll
    for (int reg = 0; reg < 16; ++reg) {
      const int rloc = wq * 64 + q * 32 + (reg & 3) + ((reg >> 2) << 3) + g * 4;
      const int row = rowBlock + rloc;
      float v0 = fmaxf(acc2[q][0][reg] + bias0, 0.0f);
      float v1 = fmaxf(acc2[q][1][reg] + bias1, 0.0f);
      if (row < nrows) {
        dst[(size_t)row * 128 + wm * 64 + l31]      = cvt_bf16(v0);
        dst[(size_t)row * 128 + wm * 64 + 32 + l31] = cvt_bf16(v1);
      }
      if constexpr (POOL) {
        float vs = v0 + v1;
#pragma unroll
        for (int m = 1; m <= 16; m <<= 1) vs += __shfl_xor(vs, m, 64);
        if (l31 == 0) Ps[wm * 256 + rloc] = vs;
      }
    }
  }
  if constexpr (POOL) {
    __syncthreads();
    if (tid < 256) {
      int row = rowBlock + tid;
      if (row < nrows) pool_out[row] = Ps[tid] + Ps[256 + tid];
    }
  }
}

// ---------------------------------------------------------------------------
// Workspace layout (bytes)
// ---------------------------------------------------------------------------
static constexpr size_t OFF_X    = 0;                          // N*128*2
static constexpr size_t OFF_E    = 5120000;                    // E*128*2
static constexpr size_t OFF_AGG  = 87040000;                   // N*128*2 (bf16)
static constexpr size_t OFF_PN1  = 92160000;                   // 65536
static constexpr size_t OFF_PN2  = OFF_PN1 + 65536;
static constexpr size_t OFF_PE1  = OFF_PN2 + 65536;
static constexpr size_t OFF_PE2  = OFF_PE1 + 65536;
static constexpr size_t OFF_PD1  = OFF_PE2 + 65536;            // 196608
static constexpr size_t OFF_PD2  = OFF_PD1 + 196608;
static constexpr size_t OFF_PM1  = OFF_PD2 + 65536;            // 131072
static constexpr size_t OFF_PM2  = OFF_PM1 + 131072;
static constexpr size_t OFF_CNT  = OFF_PM2 + 65536;            // N*4
static constexpr size_t OFF_OFFS = OFF_CNT + 80000;            // (N+1)*4
static constexpr size_t OFF_CUR  = OFF_OFFS + 80004;           // N*4
static constexpr size_t OFF_EID  = OFF_CUR + 80000;            // E*4

extern "C" void kernel_launch(void* const* d_in, const int* in_sizes, int n_in,
                              void* d_out, int out_size, void* d_ws, size_t ws_size,
                              hipStream_t stream) {
  const float* nodes = (const float*)d_in[0];
  const float* edges = (const float*)d_in[1];
  const int* senders = (const int*)d_in[2];
  const int* receivers = (const int*)d_in[3];
  const float* Wn1 = (const float*)d_in[4];  const float* bn1 = (const float*)d_in[5];
  const float* Wn2 = (const float*)d_in[6];  const float* bn2 = (const float*)d_in[7];
  const float* We1 = (const float*)d_in[8];  const float* be1 = (const float*)d_in[9];
  const float* We2 = (const float*)d_in[10]; const float* be2 = (const float*)d_in[11];
  const float* Wed1 = (const float*)d_in[12]; const float* bed1 = (const float*)d_in[13];
  const float* Wed2 = (const float*)d_in[14]; const float* bed2 = (const float*)d_in[15];
  const float* Wnd1 = (const float*)d_in[16]; const float* bnd1 = (const float*)d_in[17];
  const float* Wnd2 = (const float*)d_in[18]; const float* bnd2 = (const float*)d_in[19];

  char* ws = (char*)d_ws;
  unsigned short* xb   = (unsigned short*)(ws + OFF_X);
  unsigned short* eb   = (unsigned short*)(ws + OFF_E);
  unsigned short* aggb = (unsigned short*)(ws + OFF_AGG);
  unsigned short* Pn1  = (unsigned short*)(ws + OFF_PN1);
  unsigned short* Pn2  = (unsigned short*)(ws + OFF_PN2);
  unsigned short* Pe1  = (unsigned short*)(ws + OFF_PE1);
  unsigned short* Pe2  = (unsigned short*)(ws + OFF_PE2);
  unsigned short* Pd1  = (unsigned short*)(ws + OFF_PD1);
  unsigned short* Pd2  = (unsigned short*)(ws + OFF_PD2);
  unsigned short* Pm1  = (unsigned short*)(ws + OFF_PM1);
  unsigned short* Pm2  = (unsigned short*)(ws + OFF_PM2);
  int* cnt    = (int*)(ws + OFF_CNT);
  int* offs   = (int*)(ws + OFF_OFFS);
  int* cursor = (int*)(ws + OFF_CUR);
  int* eid    = (int*)(ws + OFF_EID);
  float* outp = (float*)d_out;

  // pack all 8 weight matrices into MFMA fragment order (bf16)
  pack_w<<<128, 256, 0, stream>>>(Wn1, Pn1, 128, 256);
  pack_w<<<128, 256, 0, stream>>>(Wn2, Pn2, 256, 128);
  pack_w<<<128, 256, 0, stream>>>(We1, Pe1, 128, 256);
  pack_w<<<128, 256, 0, stream>>>(We2, Pe2, 256, 128);
  pack_w<<<384, 256, 0, stream>>>(Wed1, Pd1, 384, 256);
  pack_w<<<128, 256, 0, stream>>>(Wed2, Pd2, 256, 128);
  pack_w<<<256, 256, 0, stream>>>(Wnd1, Pm1, 256, 256);
  pack_w<<<128, 256, 0, stream>>>(Wnd2, Pm2, 256, 128);

  // CSR for segment_sum over receivers
  hipMemsetAsync(cnt, 0, (size_t)N_NODES * 4, stream);
  hist_k<<<1250, 256, 0, stream>>>(receivers, cnt, N_EDGES);
  scan_k<<<1, 1024, 0, stream>>>(cnt, offs, cursor, N_NODES);
  fill_k<<<1250, 256, 0, stream>>>(receivers, cursor, eid, N_EDGES);

  const int nodeBlocks = (N_NODES + 255) / 256;  // 79
  const int edgeBlocks = N_EDGES / 256;          // 1250

  // embed stage
  mlp_kernel<128, 0, 0><<<nodeBlocks, 512, 0, stream>>>(
      nodes, nullptr, nullptr, nullptr, nullptr, nullptr,
      Pn1, bn1, Pn2, bn2, xb, nullptr, N_NODES);
  mlp_kernel<128, 0, 0><<<edgeBlocks, 512, 0, stream>>>(
      edges, nullptr, nullptr, nullptr, nullptr, nullptr,
      Pe1, be1, Pe2, be2, eb, nullptr, N_EDGES);

  for (int it = 0; it < 2; ++it) {
    mlp_kernel<384, 1, 0><<<edgeBlocks, 512, 0, stream>>>(
        nullptr, xb, eb, nullptr, senders, receivers,
        Pd1, bed1, Pd2, bed2, eb, nullptr, N_EDGES);
    agg_k<<<(N_NODES + 3) / 4, 256, 0, stream>>>(eb, offs, eid, aggb, N_NODES);
    mlp_kernel<256, 2, 1><<<nodeBlocks, 512, 0, stream>>>(
        nullptr, xb, nullptr, aggb, nullptr, nullptr,
        Pm1, bnd1, Pm2, bnd2, xb, outp + (size_t)it * N_NODES, N_NODES);
  }
}